// Round 3
// baseline (353.228 us; speedup 1.0000x reference)
//
#include <hip/hip_runtime.h>

typedef __attribute__((ext_vector_type(4))) float f32x4;
typedef __attribute__((ext_vector_type(4))) int   i32x4;
typedef __attribute__((ext_vector_type(8))) short bf16x8;
typedef __attribute__((ext_vector_type(4))) short s16x4;

#define HD 16
#define SQ 2048
#define DM 1024
#define DK 64

__device__ __forceinline__ short f2bf(float f){
  union { float f; unsigned u; } c; c.f = f;
  unsigned r = (c.u + 0x7FFFu + ((c.u >> 16) & 1u)) >> 16;
  return (short)r;
}
__device__ __forceinline__ float bf2f(short s){
  union { unsigned u; float f; } c; c.u = ((unsigned)(unsigned short)s) << 16;
  return c.f;
}
__device__ __forceinline__ f32x4 mfma16(bf16x8 a, bf16x8 b, f32x4 c){
  return __builtin_amdgcn_mfma_f32_16x16x32_bf16(a, b, c, 0, 0, 0);
}

// ---------------- prep kernels ----------------

__global__ void k_rope_tab(float2* __restrict__ tab){
  int i = blockIdx.x * 256 + threadIdx.x;   // SQ*32 entries
  int s = i >> 5, d2 = i & 31;
  float theta = powf(10000.0f, -(float)d2 / 32.0f);
  float ang = (float)s * theta;
  tab[i] = make_float2(cosf(ang), sinf(ang));
}

__global__ void k_cast(const float* __restrict__ x, short* __restrict__ xb){
  int i = (blockIdx.x * 256 + threadIdx.x) * 4;
  f32x4 v = *(const f32x4*)(x + i);
  s16x4 o;
  o[0] = f2bf(v[0]); o[1] = f2bf(v[1]); o[2] = f2bf(v[2]); o[3] = f2bf(v[3]);
  *(s16x4*)(xb + i) = o;
}

// W [K][N] f32 -> Wt [N][K] bf16, 4 matrices batched on z
__global__ void k_wt4(const float* __restrict__ W0, const float* __restrict__ W1,
                      const float* __restrict__ W2, const float* __restrict__ W3,
                      short* __restrict__ T0, short* __restrict__ T1,
                      short* __restrict__ T2, short* __restrict__ T3){
  __shared__ float t[32][33];
  const float* W; short* Wt;
  if (blockIdx.z == 0)      { W = W0; Wt = T0; }
  else if (blockIdx.z == 1) { W = W1; Wt = T1; }
  else if (blockIdx.z == 2) { W = W2; Wt = T2; }
  else                      { W = W3; Wt = T3; }
  int kx = blockIdx.x * 32, nx = blockIdx.y * 32;
  int lx = threadIdx.x & 31, ly = threadIdx.x >> 5;
#pragma unroll
  for (int i = 0; i < 32; i += 8)
    t[ly + i][lx] = W[(size_t)(kx + ly + i) * DM + nx + lx];
  __syncthreads();
#pragma unroll
  for (int i = 0; i < 32; i += 8)
    Wt[(size_t)(nx + ly + i) * DM + kx + lx] = f2bf(t[lx][ly + i]);
}

// ---------------- fused QKV projection GEMM ----------------
// blockIdx.y: [0,24) -> mat = y>>3 (0=Q,1=K,2=V), n0 = (y&7)*128
// Q: rope, *0.125, bf16 [B][H][S][dk]
// K: rope, bf16 [B][H][S][dk]
// V: bf16 transposed [B][H][dk][S]
__global__ __launch_bounds__(256) void k_projqkv(const short* __restrict__ A,
    const short* __restrict__ Wqt, const short* __restrict__ Wkt, const short* __restrict__ Wvt,
    const float* __restrict__ bq, const float* __restrict__ bk, const float* __restrict__ bv,
    const float2* __restrict__ rope,
    short* __restrict__ Qo, short* __restrict__ Ko, short* __restrict__ Vo)
{
  __shared__ short As[128 * 64];
  __shared__ short Bs[128 * 64];
  const int mat = blockIdx.y >> 3;
  const int n0 = (blockIdx.y & 7) * 128;
  const short* Bt  = (mat == 0) ? Wqt : (mat == 1) ? Wkt : Wvt;
  const float* bias = (mat == 0) ? bq : (mat == 1) ? bk : bv;
  const int tid = threadIdx.x;
  const int lane = tid & 63, w = tid >> 6;
  const int wr = w >> 1, wc = w & 1;
  const int l15 = lane & 15, l4 = lane >> 4;
  const int m0 = blockIdx.x * 128;
  f32x4 acc[4][4] = {};

  for (int k0 = 0; k0 < DM; k0 += 64) {
#pragma unroll
    for (int i = 0; i < 4; ++i) {
      int t = i * 256 + tid, row = t >> 3, j = t & 7;
      i32x4 va = *(const i32x4*)(A  + (size_t)(m0 + row) * DM + k0 + j * 8);
      i32x4 vb = *(const i32x4*)(Bt + (size_t)(n0 + row) * DM + k0 + j * 8);
      int db = (row * 128 + j * 16) ^ ((row & 7) << 4);
      *(i32x4*)((char*)As + db) = va;
      *(i32x4*)((char*)Bs + db) = vb;
    }
    __syncthreads();
#pragma unroll
    for (int kk = 0; kk < 64; kk += 32) {
      bf16x8 af[4], bfr[4];
#pragma unroll
      for (int mi = 0; mi < 4; ++mi) {
        int r = wr * 64 + mi * 16 + l15;
        af[mi] = *(const bf16x8*)((char*)As + ((r * 128 + kk * 2 + l4 * 16) ^ ((r & 7) << 4)));
      }
#pragma unroll
      for (int ni = 0; ni < 4; ++ni) {
        int r = wc * 64 + ni * 16 + l15;
        bfr[ni] = *(const bf16x8*)((char*)Bs + ((r * 128 + kk * 2 + l4 * 16) ^ ((r & 7) << 4)));
      }
#pragma unroll
      for (int mi = 0; mi < 4; ++mi)
#pragma unroll
        for (int ni = 0; ni < 4; ++ni)
          acc[mi][ni] = mfma16(af[mi], bfr[ni], acc[mi][ni]);
    }
    __syncthreads();
  }

#pragma unroll
  for (int mi = 0; mi < 4; ++mi) {
#pragma unroll
    for (int ni = 0; ni < 4; ++ni) {
      int n = n0 + wc * 64 + ni * 16 + l15;
      float bv2 = bias[n];
      if (mat == 2) {
        s16x4 pk;
        int mb = m0 + wr * 64 + mi * 16 + l4 * 4;
#pragma unroll
        for (int r2 = 0; r2 < 4; ++r2) pk[r2] = f2bf(acc[mi][ni][r2] + bv2);
        int b = mb >> 11, s = mb & 2047, h = n >> 6, d = n & 63;
        *(s16x4*)(Vo + ((size_t)((b * HD + h) * DK + d)) * SQ + s) = pk;
      } else {
        short* outp = (mat == 0) ? Qo : Ko;
        float sc = (mat == 0) ? 0.125f : 1.0f;
#pragma unroll
        for (int r2 = 0; r2 < 4; ++r2) {
          int m = m0 + wr * 64 + mi * 16 + l4 * 4 + r2;
          float v = acc[mi][ni][r2] + bv2;
          float pr = __shfl_xor(v, 1);
          int s = m & 2047, d = n & 63;
          float2 cs = rope[(s << 5) + (d >> 1)];
          v = (d & 1) ? (v * cs.x + pr * cs.y) : (v * cs.x - pr * cs.y);
          v *= sc;
          int b = m >> 11, h = n >> 6;
          outp[((size_t)((b * HD + h) * SQ + s)) * DK + d] = f2bf(v);
        }
      }
    }
  }
}

// ---------------- O projection: 64x128 tile, grid (64,8) ----------------
__global__ __launch_bounds__(256) void k_projO(const short* __restrict__ A, const short* __restrict__ Bt,
                                               const float* __restrict__ bias, float* __restrict__ out)
{
  __shared__ short As[64 * 64];
  __shared__ short Bs[128 * 64];
  const int tid = threadIdx.x;
  const int lane = tid & 63, w = tid >> 6;
  const int wr = w >> 1, wc = w & 1;
  const int l15 = lane & 15, l4 = lane >> 4;
  const int m0 = blockIdx.x * 64, n0 = blockIdx.y * 128;
  f32x4 acc[2][4] = {};

  for (int k0 = 0; k0 < DM; k0 += 64) {
#pragma unroll
    for (int i = 0; i < 2; ++i) {
      int t = i * 256 + tid, row = t >> 3, j = t & 7;
      i32x4 va = *(const i32x4*)(A + (size_t)(m0 + row) * DM + k0 + j * 8);
      *(i32x4*)((char*)As + ((row * 128 + j * 16) ^ ((row & 7) << 4))) = va;
    }
#pragma unroll
    for (int i = 0; i < 4; ++i) {
      int t = i * 256 + tid, row = t >> 3, j = t & 7;
      i32x4 vb = *(const i32x4*)(Bt + (size_t)(n0 + row) * DM + k0 + j * 8);
      *(i32x4*)((char*)Bs + ((row * 128 + j * 16) ^ ((row & 7) << 4))) = vb;
    }
    __syncthreads();
#pragma unroll
    for (int kk = 0; kk < 64; kk += 32) {
      bf16x8 af[2], bfr[4];
#pragma unroll
      for (int mi = 0; mi < 2; ++mi) {
        int r = wr * 32 + mi * 16 + l15;
        af[mi] = *(const bf16x8*)((char*)As + ((r * 128 + kk * 2 + l4 * 16) ^ ((r & 7) << 4)));
      }
#pragma unroll
      for (int ni = 0; ni < 4; ++ni) {
        int r = wc * 64 + ni * 16 + l15;
        bfr[ni] = *(const bf16x8*)((char*)Bs + ((r * 128 + kk * 2 + l4 * 16) ^ ((r & 7) << 4)));
      }
#pragma unroll
      for (int mi = 0; mi < 2; ++mi)
#pragma unroll
        for (int ni = 0; ni < 4; ++ni)
          acc[mi][ni] = mfma16(af[mi], bfr[ni], acc[mi][ni]);
    }
    __syncthreads();
  }

#pragma unroll
  for (int mi = 0; mi < 2; ++mi)
#pragma unroll
    for (int ni = 0; ni < 4; ++ni) {
      int n = n0 + wc * 64 + ni * 16 + l15;
      float bv2 = bias[n];
#pragma unroll
      for (int r2 = 0; r2 < 4; ++r2) {
        int m = m0 + wr * 32 + mi * 16 + l4 * 4 + r2;
        out[(size_t)m * DM + n] = acc[mi][ni][r2] + bv2;
      }
    }
}

// ---------------- fused attention: rowsum sweep + write/PV sweep ----------------
__global__ __launch_bounds__(256) void k_attn2(const short* __restrict__ Q, const short* __restrict__ K,
    const short* __restrict__ Vt, float* __restrict__ attn_out, short* __restrict__ ctx)
{
  __shared__ short Qs[128 * 64];   // row stride 128B, swz ((r&7)<<4)
  __shared__ short Ks[128 * 64];   // row stride 128B, swz ((r&7)<<4)
  __shared__ short Vs[64 * 128];   // row stride 256B, swz ((r&15)<<4)
  __shared__ short Ps[128 * 128];  // row stride 256B, swz ((r&15)<<4)
  const int bh = blockIdx.y, qt = blockIdx.x;
  const int tid = threadIdx.x, lane = tid & 63, w = tid >> 6;
  const int l15 = lane & 15, l4 = lane >> 4;
  const short* Qg = Q + (size_t)(bh * SQ + qt * 128) * DK;
  const short* Kg = K + (size_t)bh * SQ * DK;
  const short* Vg = Vt + (size_t)bh * DK * SQ;

  // stage Q once
#pragma unroll
  for (int i = 0; i < 4; ++i) {
    int t = i * 256 + tid, row = t >> 3, j = t & 7;
    i32x4 v = *(const i32x4*)(Qg + row * 64 + j * 8);
    *(i32x4*)((char*)Qs + ((row * 128 + j * 16) ^ ((row & 7) << 4))) = v;
  }

  // ---- sweep 1: rowsums of exp(scores), kept in registers ----
  float rs[2][4] = {};
  for (int kt = 0; kt < 16; ++kt) {
#pragma unroll
    for (int i = 0; i < 4; ++i) {
      int t = i * 256 + tid, row = t >> 3, j = t & 7;
      i32x4 v = *(const i32x4*)(Kg + (size_t)(kt * 128 + row) * 64 + j * 8);
      *(i32x4*)((char*)Ks + ((row * 128 + j * 16) ^ ((row & 7) << 4))) = v;
    }
    __syncthreads();
    f32x4 p[2][8] = {};
#pragma unroll
    for (int kk = 0; kk < 64; kk += 32) {
      bf16x8 aq[2];
#pragma unroll
      for (int mi = 0; mi < 2; ++mi) {
        int r = w * 32 + mi * 16 + l15;
        aq[mi] = *(const bf16x8*)((char*)Qs + ((r * 128 + kk * 2 + l4 * 16) ^ ((r & 7) << 4)));
      }
#pragma unroll
      for (int ni = 0; ni < 8; ++ni) {
        int r = ni * 16 + l15;
        bf16x8 bk = *(const bf16x8*)((char*)Ks + ((r * 128 + kk * 2 + l4 * 16) ^ ((r & 7) << 4)));
        p[0][ni] = mfma16(aq[0], bk, p[0][ni]);
        p[1][ni] = mfma16(aq[1], bk, p[1][ni]);
      }
    }
#pragma unroll
    for (int mi = 0; mi < 2; ++mi)
#pragma unroll
      for (int ni = 0; ni < 8; ++ni)
#pragma unroll
        for (int r2 = 0; r2 < 4; ++r2)
          rs[mi][r2] += __expf(p[mi][ni][r2]);
    __syncthreads();
  }
  // butterfly over the 16 column-lanes: every lane ends with its 8 row-inverses
  float rinv_r[2][4];
#pragma unroll
  for (int mi = 0; mi < 2; ++mi)
#pragma unroll
    for (int r2 = 0; r2 < 4; ++r2) {
      float v = rs[mi][r2];
      v += __shfl_xor(v, 1); v += __shfl_xor(v, 2);
      v += __shfl_xor(v, 4); v += __shfl_xor(v, 8);
      rinv_r[mi][r2] = 1.0f / v;
    }

  // ---- sweep 2: recompute, normalize, write weights, PV ----
  f32x4 c[2][4] = {};
  float* attn_base = attn_out + ((size_t)(bh * SQ + qt * 128)) * SQ;

  for (int kt = 0; kt < 16; ++kt) {
#pragma unroll
    for (int i = 0; i < 4; ++i) {
      int t = i * 256 + tid, row = t >> 3, j = t & 7;
      i32x4 v = *(const i32x4*)(Kg + (size_t)(kt * 128 + row) * 64 + j * 8);
      *(i32x4*)((char*)Ks + ((row * 128 + j * 16) ^ ((row & 7) << 4))) = v;
    }
#pragma unroll
    for (int i = 0; i < 4; ++i) {
      int t = i * 256 + tid, row = t >> 4, cc = t & 15;  // 64 rows x 16 chunks
      i32x4 v = *(const i32x4*)(Vg + (size_t)row * SQ + kt * 128 + cc * 8);
      *(i32x4*)((char*)Vs + ((row * 256 + cc * 16) ^ ((row & 15) << 4))) = v;
    }
    __syncthreads();
    // QK^T (identical sequence to sweep 1 -> identical values)
    f32x4 p[2][8] = {};
#pragma unroll
    for (int kk = 0; kk < 64; kk += 32) {
      bf16x8 aq[2];
#pragma unroll
      for (int mi = 0; mi < 2; ++mi) {
        int r = w * 32 + mi * 16 + l15;
        aq[mi] = *(const bf16x8*)((char*)Qs + ((r * 128 + kk * 2 + l4 * 16) ^ ((r & 7) << 4)));
      }
#pragma unroll
      for (int ni = 0; ni < 8; ++ni) {
        int r = ni * 16 + l15;
        bf16x8 bk = *(const bf16x8*)((char*)Ks + ((r * 128 + kk * 2 + l4 * 16) ^ ((r & 7) << 4)));
        p[0][ni] = mfma16(aq[0], bk, p[0][ni]);
        p[1][ni] = mfma16(aq[1], bk, p[1][ni]);
      }
    }
    // exp * rinv -> bf16 into Ps
#pragma unroll
    for (int mi = 0; mi < 2; ++mi)
#pragma unroll
      for (int ni = 0; ni < 8; ++ni)
#pragma unroll
        for (int r2 = 0; r2 < 4; ++r2) {
          int row = w * 32 + mi * 16 + l4 * 4 + r2;
          float v = __expf(p[mi][ni][r2]) * rinv_r[mi][r2];
          int col = ni * 16 + l15;
          *(short*)((char*)Ps + ((row * 256 + col * 2) ^ ((row & 15) << 4))) = f2bf(v);
        }
    __syncthreads();
    // coalesced f32 write of the normalized 128x128 tile
    {
      int r0 = tid >> 5;            // 8 rows per round
      int c4 = (tid & 31) * 4;      // 32 chunks x 4 f32 = 128 cols
#pragma unroll
      for (int it = 0; it < 16; ++it) {
        int row = it * 8 + r0;
        s16x4 pv = *(const s16x4*)((char*)Ps + ((row * 256 + c4 * 2) ^ ((row & 15) << 4)));
        f32x4 o;
        o[0] = bf2f(pv[0]); o[1] = bf2f(pv[1]); o[2] = bf2f(pv[2]); o[3] = bf2f(pv[3]);
        *(f32x4*)(attn_base + (size_t)row * SQ + kt * 128 + c4) = o;
      }
    }
    // PV: c[q][d] += P[q][k] * V[k][d], k over 128
#pragma unroll
    for (int kk = 0; kk < 128; kk += 32) {
      bf16x8 ap[2];
#pragma unroll
      for (int mi = 0; mi < 2; ++mi) {
        int r = w * 32 + mi * 16 + l15;
        ap[mi] = *(const bf16x8*)((char*)Ps + ((r * 256 + kk * 2 + l4 * 16) ^ ((r & 15) << 4)));
      }
#pragma unroll
      for (int ni = 0; ni < 4; ++ni) {
        int r = ni * 16 + l15;
        bf16x8 bv = *(const bf16x8*)((char*)Vs + ((r * 256 + kk * 2 + l4 * 16) ^ ((r & 15) << 4)));
        c[0][ni] = mfma16(ap[0], bv, c[0][ni]);
        c[1][ni] = mfma16(ap[1], bv, c[1][ni]);
      }
    }
    __syncthreads();
  }
  // ctx -> bf16 [B][S][H*dk]
  int b = bh >> 4, h = bh & 15;
#pragma unroll
  for (int mi = 0; mi < 2; ++mi)
#pragma unroll
    for (int ni = 0; ni < 4; ++ni)
#pragma unroll
      for (int r2 = 0; r2 < 4; ++r2) {
        int s = qt * 128 + w * 32 + mi * 16 + l4 * 4 + r2;
        int d = ni * 16 + l15;
        ctx[((size_t)(b * SQ + s)) * DM + h * DK + d] = f2bf(c[mi][ni][r2]);
      }
}

extern "C" void kernel_launch(void* const* d_in, const int* in_sizes, int n_in,
                              void* d_out, int out_size, void* d_ws, size_t ws_size,
                              hipStream_t stream)
{
  const float* x  = (const float*)d_in[0];
  const float* Wq = (const float*)d_in[1];
  const float* bq = (const float*)d_in[2];
  const float* Wk = (const float*)d_in[3];
  const float* bk = (const float*)d_in[4];
  const float* Wv = (const float*)d_in[5];
  const float* bv = (const float*)d_in[6];
  const float* Wo = (const float*)d_in[7];
  const float* bo = (const float*)d_in[8];

  char* p = (char*)d_ws;
  float2* rope = (float2*)p;  p += (size_t)SQ * 32 * sizeof(float2);
  short* xb  = (short*)p;     p += (size_t)4096 * DM * 2;
  short* Wqt = (short*)p;     p += (size_t)DM * DM * 2;
  short* Wkt = (short*)p;     p += (size_t)DM * DM * 2;
  short* Wvt = (short*)p;     p += (size_t)DM * DM * 2;
  short* Wot = (short*)p;     p += (size_t)DM * DM * 2;
  short* Qr  = (short*)p;     p += (size_t)2 * HD * SQ * DK * 2;
  short* Kr  = (short*)p;     p += (size_t)2 * HD * SQ * DK * 2;
  short* Vtr = (short*)p;     p += (size_t)2 * HD * SQ * DK * 2;
  short* ctx = (short*)p;     p += (size_t)4096 * DM * 2;

  k_rope_tab<<<SQ * 32 / 256, 256, 0, stream>>>(rope);
  k_cast<<<4096 * DM / 1024, 256, 0, stream>>>(x, xb);
  k_wt4<<<dim3(32, 32, 4), 256, 0, stream>>>(Wq, Wk, Wv, Wo, Wqt, Wkt, Wvt, Wot);
  k_projqkv<<<dim3(32, 24), 256, 0, stream>>>(xb, Wqt, Wkt, Wvt, bq, bk, bv, rope, Qr, Kr, Vtr);
  float* attn = (float*)d_out + (size_t)2 * SQ * DM;
  k_attn2<<<dim3(16, 32), 256, 0, stream>>>(Qr, Kr, Vtr, attn, ctx);
  k_projO<<<dim3(64, 8), 256, 0, stream>>>(ctx, Wot, bo, (float*)d_out);
}

// Round 4
// 326.223 us; speedup vs baseline: 1.0828x; 1.0828x over previous
//
#include <hip/hip_runtime.h>

typedef __attribute__((ext_vector_type(4))) float f32x4;
typedef __attribute__((ext_vector_type(4))) int   i32x4;
typedef __attribute__((ext_vector_type(8))) short bf16x8;
typedef __attribute__((ext_vector_type(4))) short s16x4;

#define HD 16
#define SQ 2048
#define DM 1024
#define DK 64
#define QSCALE 0.18033688011112042f   // 0.125 * log2(e)

__device__ __forceinline__ short f2bf(float f){
  union { float f; unsigned u; } c; c.f = f;
  unsigned r = (c.u + 0x7FFFu + ((c.u >> 16) & 1u)) >> 16;
  return (short)r;
}
__device__ __forceinline__ f32x4 mfma16(bf16x8 a, bf16x8 b, f32x4 c){
  return __builtin_amdgcn_mfma_f32_16x16x32_bf16(a, b, c, 0, 0, 0);
}
// async global->LDS, 16B per lane. dst must be wave-uniform; src is per-lane.
__device__ __forceinline__ void gload16(const void* g, void* l){
  __builtin_amdgcn_global_load_lds(
      (const __attribute__((address_space(1))) unsigned*)g,
      (__attribute__((address_space(3))) unsigned*)l, 16, 0, 0);
}

// ---------------- prep kernels ----------------

__global__ void k_rope_tab(float2* __restrict__ tab){
  int i = blockIdx.x * 256 + threadIdx.x;   // SQ*32 entries
  int s = i >> 5, d2 = i & 31;
  float theta = powf(10000.0f, -(float)d2 / 32.0f);
  float ang = (float)s * theta;
  tab[i] = make_float2(cosf(ang), sinf(ang));
}

__global__ void k_cast(const float* __restrict__ x, short* __restrict__ xb){
  int i = (blockIdx.x * 256 + threadIdx.x) * 4;
  f32x4 v = *(const f32x4*)(x + i);
  s16x4 o;
  o[0] = f2bf(v[0]); o[1] = f2bf(v[1]); o[2] = f2bf(v[2]); o[3] = f2bf(v[3]);
  *(s16x4*)(xb + i) = o;
}

// W [K][N] f32 -> Wt [N][K] bf16, 4 matrices batched on z
__global__ void k_wt4(const float* __restrict__ W0, const float* __restrict__ W1,
                      const float* __restrict__ W2, const float* __restrict__ W3,
                      short* __restrict__ T0, short* __restrict__ T1,
                      short* __restrict__ T2, short* __restrict__ T3){
  __shared__ float t[32][33];
  const float* W; short* Wt;
  if (blockIdx.z == 0)      { W = W0; Wt = T0; }
  else if (blockIdx.z == 1) { W = W1; Wt = T1; }
  else if (blockIdx.z == 2) { W = W2; Wt = T2; }
  else                      { W = W3; Wt = T3; }
  int kx = blockIdx.x * 32, nx = blockIdx.y * 32;
  int lx = threadIdx.x & 31, ly = threadIdx.x >> 5;
#pragma unroll
  for (int i = 0; i < 32; i += 8)
    t[ly + i][lx] = W[(size_t)(kx + ly + i) * DM + nx + lx];
  __syncthreads();
#pragma unroll
  for (int i = 0; i < 32; i += 8)
    Wt[(size_t)(nx + ly + i) * DM + kx + lx] = f2bf(t[lx][ly + i]);
}

// ---------------- fused QKV projection GEMM ----------------
// blockIdx.y: [0,24) -> mat = y>>3 (0=Q,1=K,2=V), n0 = (y&7)*128
__global__ __launch_bounds__(256) void k_projqkv(const short* __restrict__ A,
    const short* __restrict__ Wqt, const short* __restrict__ Wkt, const short* __restrict__ Wvt,
    const float* __restrict__ bq, const float* __restrict__ bk, const float* __restrict__ bv,
    const float2* __restrict__ rope,
    short* __restrict__ Qo, short* __restrict__ Ko, short* __restrict__ Vo)
{
  __shared__ short As[128 * 64];
  __shared__ short Bs[128 * 64];
  const int mat = blockIdx.y >> 3;
  const int n0 = (blockIdx.y & 7) * 128;
  const short* Bt  = (mat == 0) ? Wqt : (mat == 1) ? Wkt : Wvt;
  const float* bias = (mat == 0) ? bq : (mat == 1) ? bk : bv;
  const int tid = threadIdx.x;
  const int lane = tid & 63, w = tid >> 6;
  const int wr = w >> 1, wc = w & 1;
  const int l15 = lane & 15, l4 = lane >> 4;
  const int m0 = blockIdx.x * 128;
  f32x4 acc[4][4] = {};

  for (int k0 = 0; k0 < DM; k0 += 64) {
#pragma unroll
    for (int i = 0; i < 4; ++i) {
      int c = w * 4 + i;
      int row = c * 8 + (lane >> 3);
      int so = (((lane & 7) * 16) ^ ((row & 7) << 4)) >> 1;   // shorts, pre-swizzled
      gload16(A  + (size_t)(m0 + row) * DM + k0 + so, (char*)As + c * 1024);
      gload16(Bt + (size_t)(n0 + row) * DM + k0 + so, (char*)Bs + c * 1024);
    }
    __syncthreads();
#pragma unroll
    for (int kk = 0; kk < 64; kk += 32) {
      bf16x8 af[4], bfr[4];
#pragma unroll
      for (int mi = 0; mi < 4; ++mi) {
        int r = wr * 64 + mi * 16 + l15;
        af[mi] = *(const bf16x8*)((char*)As + ((r * 128 + kk * 2 + l4 * 16) ^ ((r & 7) << 4)));
      }
#pragma unroll
      for (int ni = 0; ni < 4; ++ni) {
        int r = wc * 64 + ni * 16 + l15;
        bfr[ni] = *(const bf16x8*)((char*)Bs + ((r * 128 + kk * 2 + l4 * 16) ^ ((r & 7) << 4)));
      }
#pragma unroll
      for (int mi = 0; mi < 4; ++mi)
#pragma unroll
        for (int ni = 0; ni < 4; ++ni)
          acc[mi][ni] = mfma16(af[mi], bfr[ni], acc[mi][ni]);
    }
    __syncthreads();
  }

#pragma unroll
  for (int mi = 0; mi < 4; ++mi) {
#pragma unroll
    for (int ni = 0; ni < 4; ++ni) {
      int n = n0 + wc * 64 + ni * 16 + l15;
      float bv2 = bias[n];
      if (mat == 2) {
        s16x4 pk;
        int mb = m0 + wr * 64 + mi * 16 + l4 * 4;
#pragma unroll
        for (int r2 = 0; r2 < 4; ++r2) pk[r2] = f2bf(acc[mi][ni][r2] + bv2);
        int b = mb >> 11, s = mb & 2047, h = n >> 6, d = n & 63;
        *(s16x4*)(Vo + ((size_t)((b * HD + h) * DK + d)) * SQ + s) = pk;
      } else {
        short* outp = (mat == 0) ? Qo : Ko;
        float sc = (mat == 0) ? QSCALE : 1.0f;
#pragma unroll
        for (int r2 = 0; r2 < 4; ++r2) {
          int m = m0 + wr * 64 + mi * 16 + l4 * 4 + r2;
          float v = acc[mi][ni][r2] + bv2;
          float pr = __shfl_xor(v, 1);
          int s = m & 2047, d = n & 63;
          float2 cs = rope[(s << 5) + (d >> 1)];
          v = (d & 1) ? (v * cs.x + pr * cs.y) : (v * cs.x - pr * cs.y);
          v *= sc;
          int b = m >> 11, h = n >> 6;
          outp[((size_t)((b * HD + h) * SQ + s)) * DK + d] = f2bf(v);
        }
      }
    }
  }
}

// ---------------- O projection: 64x128 tile, grid (64,8) ----------------
__global__ __launch_bounds__(256) void k_projO(const short* __restrict__ A, const short* __restrict__ Bt,
                                               const float* __restrict__ bias, float* __restrict__ out)
{
  __shared__ short As[64 * 64];
  __shared__ short Bs[128 * 64];
  const int tid = threadIdx.x;
  const int lane = tid & 63, w = tid >> 6;
  const int wr = w >> 1, wc = w & 1;
  const int l15 = lane & 15, l4 = lane >> 4;
  const int m0 = blockIdx.x * 64, n0 = blockIdx.y * 128;
  f32x4 acc[2][4] = {};

  for (int k0 = 0; k0 < DM; k0 += 64) {
#pragma unroll
    for (int i = 0; i < 2; ++i) {
      int c = w * 2 + i;
      int row = c * 8 + (lane >> 3);
      int so = (((lane & 7) * 16) ^ ((row & 7) << 4)) >> 1;
      gload16(A + (size_t)(m0 + row) * DM + k0 + so, (char*)As + c * 1024);
    }
#pragma unroll
    for (int i = 0; i < 4; ++i) {
      int c = w * 4 + i;
      int row = c * 8 + (lane >> 3);
      int so = (((lane & 7) * 16) ^ ((row & 7) << 4)) >> 1;
      gload16(Bt + (size_t)(n0 + row) * DM + k0 + so, (char*)Bs + c * 1024);
    }
    __syncthreads();
#pragma unroll
    for (int kk = 0; kk < 64; kk += 32) {
      bf16x8 af[2], bfr[4];
#pragma unroll
      for (int mi = 0; mi < 2; ++mi) {
        int r = wr * 32 + mi * 16 + l15;
        af[mi] = *(const bf16x8*)((char*)As + ((r * 128 + kk * 2 + l4 * 16) ^ ((r & 7) << 4)));
      }
#pragma unroll
      for (int ni = 0; ni < 4; ++ni) {
        int r = wc * 64 + ni * 16 + l15;
        bfr[ni] = *(const bf16x8*)((char*)Bs + ((r * 128 + kk * 2 + l4 * 16) ^ ((r & 7) << 4)));
      }
#pragma unroll
      for (int mi = 0; mi < 2; ++mi)
#pragma unroll
        for (int ni = 0; ni < 4; ++ni)
          acc[mi][ni] = mfma16(af[mi], bfr[ni], acc[mi][ni]);
    }
    __syncthreads();
  }

#pragma unroll
  for (int mi = 0; mi < 2; ++mi)
#pragma unroll
    for (int ni = 0; ni < 4; ++ni) {
      int n = n0 + wc * 64 + ni * 16 + l15;
      float bv2 = bias[n];
#pragma unroll
      for (int r2 = 0; r2 < 4; ++r2) {
        int m = m0 + wr * 32 + mi * 16 + l4 * 4 + r2;
        out[(size_t)m * DM + n] = acc[mi][ni][r2] + bv2;
      }
    }
}

// ---------------- fused attention ----------------
// Scores arrive pre-scaled by log2(e): weights = exp2(p)/sum(exp2(p)).
__global__ __launch_bounds__(256) void k_attn2(const short* __restrict__ Q, const short* __restrict__ K,
    const short* __restrict__ Vt, float* __restrict__ attn_out, short* __restrict__ ctx)
{
  __shared__ short Qs[128 * 64];   // row 128B, swz ((r&7)<<4)
  __shared__ short Ks[128 * 64];   // row 128B, swz ((r&7)<<4)
  __shared__ short Vs[64 * 128];   // row 256B, swz ((r&15)<<4)
  __shared__ short Ps[128 * 128];  // row 256B, swz ((r&15)<<4); warp-private bands
  const int bh = blockIdx.y, qt = blockIdx.x;
  const int tid = threadIdx.x, lane = tid & 63, w = tid >> 6;
  const int l15 = lane & 15, l4 = lane >> 4;
  const short* Qg = Q + (size_t)(bh * SQ + qt * 128) * DK;
  const short* Kg = K + (size_t)bh * SQ * DK;
  const short* Vg = Vt + (size_t)bh * DK * SQ;

  // stage Q once (async DMA, pre-swizzled source)
#pragma unroll
  for (int i = 0; i < 4; ++i) {
    int c = w * 4 + i;
    int row = c * 8 + (lane >> 3);
    int so = (((lane & 7) * 16) ^ ((row & 7) << 4)) >> 1;
    gload16(Qg + row * 64 + so, (char*)Qs + c * 1024);
  }

  // ---- sweep 1: rowsums of exp2(scores) in registers ----
  float rs[2][4] = {};
  for (int kt = 0; kt < 16; ++kt) {
#pragma unroll
    for (int i = 0; i < 4; ++i) {
      int c = w * 4 + i;
      int row = c * 8 + (lane >> 3);
      int so = (((lane & 7) * 16) ^ ((row & 7) << 4)) >> 1;
      gload16(Kg + (size_t)(kt * 128 + row) * 64 + so, (char*)Ks + c * 1024);
    }
    __syncthreads();
    f32x4 p[2][8] = {};
#pragma unroll
    for (int kk = 0; kk < 64; kk += 32) {
      bf16x8 aq[2];
#pragma unroll
      for (int mi = 0; mi < 2; ++mi) {
        int r = w * 32 + mi * 16 + l15;
        aq[mi] = *(const bf16x8*)((char*)Qs + ((r * 128 + kk * 2 + l4 * 16) ^ ((r & 7) << 4)));
      }
#pragma unroll
      for (int ni = 0; ni < 8; ++ni) {
        int r = ni * 16 + l15;
        bf16x8 bk = *(const bf16x8*)((char*)Ks + ((r * 128 + kk * 2 + l4 * 16) ^ ((r & 7) << 4)));
        p[0][ni] = mfma16(aq[0], bk, p[0][ni]);
        p[1][ni] = mfma16(aq[1], bk, p[1][ni]);
      }
    }
#pragma unroll
    for (int mi = 0; mi < 2; ++mi)
#pragma unroll
      for (int ni = 0; ni < 8; ++ni)
#pragma unroll
        for (int r2 = 0; r2 < 4; ++r2)
          rs[mi][r2] += exp2f(p[mi][ni][r2]);
    __syncthreads();
  }
  // butterfly over the 16 column-lanes
  float rinv_r[2][4];
#pragma unroll
  for (int mi = 0; mi < 2; ++mi)
#pragma unroll
    for (int r2 = 0; r2 < 4; ++r2) {
      float v = rs[mi][r2];
      v += __shfl_xor(v, 1); v += __shfl_xor(v, 2);
      v += __shfl_xor(v, 4); v += __shfl_xor(v, 8);
      rinv_r[mi][r2] = 1.0f / v;
    }

  // ---- sweep 2: recompute, write exact-f32 weights from regs, PV ----
  f32x4 c[2][4] = {};
  float* attn_base = attn_out + ((size_t)(bh * SQ + qt * 128)) * SQ;

  for (int kt = 0; kt < 16; ++kt) {
#pragma unroll
    for (int i = 0; i < 4; ++i) {
      int c2 = w * 4 + i;
      int row = c2 * 8 + (lane >> 3);
      int so = (((lane & 7) * 16) ^ ((row & 7) << 4)) >> 1;
      gload16(Kg + (size_t)(kt * 128 + row) * 64 + so, (char*)Ks + c2 * 1024);
    }
#pragma unroll
    for (int i = 0; i < 4; ++i) {
      int c2 = w * 4 + i;
      int row = c2 * 4 + (lane >> 4);
      int so = (((lane & 15) * 16) ^ ((row & 15) << 4)) >> 1;
      gload16(Vg + (size_t)row * SQ + kt * 128 + so, (char*)Vs + c2 * 1024);
    }
    __syncthreads();
    // QK^T — identical op order to sweep 1 -> bitwise-identical p
    f32x4 p[2][8] = {};
#pragma unroll
    for (int kk = 0; kk < 64; kk += 32) {
      bf16x8 aq[2];
#pragma unroll
      for (int mi = 0; mi < 2; ++mi) {
        int r = w * 32 + mi * 16 + l15;
        aq[mi] = *(const bf16x8*)((char*)Qs + ((r * 128 + kk * 2 + l4 * 16) ^ ((r & 7) << 4)));
      }
#pragma unroll
      for (int ni = 0; ni < 8; ++ni) {
        int r = ni * 16 + l15;
        bf16x8 bk = *(const bf16x8*)((char*)Ks + ((r * 128 + kk * 2 + l4 * 16) ^ ((r & 7) << 4)));
        p[0][ni] = mfma16(aq[0], bk, p[0][ni]);
        p[1][ni] = mfma16(aq[1], bk, p[1][ni]);
      }
    }
    // normalize: exact f32 store to d_out + bf16 into warp-private Ps band
#pragma unroll
    for (int mi = 0; mi < 2; ++mi)
#pragma unroll
      for (int ni = 0; ni < 8; ++ni)
#pragma unroll
        for (int r2 = 0; r2 < 4; ++r2) {
          int row = w * 32 + mi * 16 + l4 * 4 + r2;
          int col = ni * 16 + l15;
          float wgt = exp2f(p[mi][ni][r2]) * rinv_r[mi][r2];
          attn_base[(size_t)row * SQ + kt * 128 + col] = wgt;
          *(short*)((char*)Ps + ((row * 256 + col * 2) ^ ((row & 15) << 4))) = f2bf(wgt);
        }
    // PV: c[q][d] += P[q][k] * V[k][d]  (Ps band is warp-private; no barrier)
#pragma unroll
    for (int kk = 0; kk < 128; kk += 32) {
      bf16x8 ap[2];
#pragma unroll
      for (int mi = 0; mi < 2; ++mi) {
        int r = w * 32 + mi * 16 + l15;
        ap[mi] = *(const bf16x8*)((char*)Ps + ((r * 256 + kk * 2 + l4 * 16) ^ ((r & 15) << 4)));
      }
#pragma unroll
      for (int ni = 0; ni < 4; ++ni) {
        int r = ni * 16 + l15;
        bf16x8 bv = *(const bf16x8*)((char*)Vs + ((r * 256 + kk * 2 + l4 * 16) ^ ((r & 15) << 4)));
        c[0][ni] = mfma16(ap[0], bv, c[0][ni]);
        c[1][ni] = mfma16(ap[1], bv, c[1][ni]);
      }
    }
    __syncthreads();
  }
  // ctx -> bf16 [B][S][H*dk]
  int b = bh >> 4, h = bh & 15;
#pragma unroll
  for (int mi = 0; mi < 2; ++mi)
#pragma unroll
    for (int ni = 0; ni < 4; ++ni)
#pragma unroll
      for (int r2 = 0; r2 < 4; ++r2) {
        int s = qt * 128 + w * 32 + mi * 16 + l4 * 4 + r2;
        int d = ni * 16 + l15;
        ctx[((size_t)(b * SQ + s)) * DM + h * DK + d] = f2bf(c[mi][ni][r2]);
      }
}

extern "C" void kernel_launch(void* const* d_in, const int* in_sizes, int n_in,
                              void* d_out, int out_size, void* d_ws, size_t ws_size,
                              hipStream_t stream)
{
  const float* x  = (const float*)d_in[0];
  const float* Wq = (const float*)d_in[1];
  const float* bq = (const float*)d_in[2];
  const float* Wk = (const float*)d_in[3];
  const float* bk = (const float*)d_in[4];
  const float* Wv = (const float*)d_in[5];
  const float* bv = (const float*)d_in[6];
  const float* Wo = (const float*)d_in[7];
  const float* bo = (const float*)d_in[8];

  char* p = (char*)d_ws;
  float2* rope = (float2*)p;  p += (size_t)SQ * 32 * sizeof(float2);
  short* xb  = (short*)p;     p += (size_t)4096 * DM * 2;
  short* Wqt = (short*)p;     p += (size_t)DM * DM * 2;
  short* Wkt = (short*)p;     p += (size_t)DM * DM * 2;
  short* Wvt = (short*)p;     p += (size_t)DM * DM * 2;
  short* Wot = (short*)p;     p += (size_t)DM * DM * 2;
  short* Qr  = (short*)p;     p += (size_t)2 * HD * SQ * DK * 2;
  short* Kr  = (short*)p;     p += (size_t)2 * HD * SQ * DK * 2;
  short* Vtr = (short*)p;     p += (size_t)2 * HD * SQ * DK * 2;
  short* ctx = (short*)p;     p += (size_t)4096 * DM * 2;

  k_rope_tab<<<SQ * 32 / 256, 256, 0, stream>>>(rope);
  k_cast<<<4096 * DM / 1024, 256, 0, stream>>>(x, xb);
  k_wt4<<<dim3(32, 32, 4), 256, 0, stream>>>(Wq, Wk, Wv, Wo, Wqt, Wkt, Wvt, Wot);
  k_projqkv<<<dim3(32, 24), 256, 0, stream>>>(xb, Wqt, Wkt, Wvt, bq, bk, bv, rope, Qr, Kr, Vtr);
  float* attn = (float*)d_out + (size_t)2 * SQ * DM;
  k_attn2<<<dim3(16, 32), 256, 0, stream>>>(Qr, Kr, Vtr, attn, ctx);
  k_projO<<<dim3(64, 8), 256, 0, stream>>>(ctx, Wot, bo, (float*)d_out);
}